// Round 10
// baseline (372.823 us; speedup 1.0000x reference)
//
#include <hip/hip_runtime.h>
#include <hip/hip_bf16.h>

#define NTOK 2048
#define NHEADS 12
#define HDIM 64
#define DIM 768
#define BATCH 4
// exp2-domain: p = exp(QK*0.125 + bias - 16) = exp2(QK*SC2 + bias*LOG2E - SHIFT2)
#define SC2_    0.18033688011112042f
#define LOG2E_  1.4426950408889634f
#define SHIFT2_ 23.083120654223415f

typedef __attribute__((ext_vector_type(8))) short short8;
typedef __attribute__((ext_vector_type(4))) float f32x4;
typedef __attribute__((ext_vector_type(16))) float f32x16;

__device__ __forceinline__ short f2bf(float f) {
  union { float f; unsigned u; } v; v.f = f;
  unsigned r = v.u + 0x7fffu + ((v.u >> 16) & 1u);
  return (short)(r >> 16);
}

__device__ __forceinline__ f32x4 mfma_bf16(short8 a, short8 b, f32x4 c) {
  return __builtin_amdgcn_mfma_f32_16x16x32_bf16(a, b, c, 0, 0, 0);
}

__device__ __forceinline__ f32x16 mfma32(short8 a, short8 b, f32x16 c) {
  return __builtin_amdgcn_mfma_f32_32x32x16_bf16(a, b, c, 0, 0, 0);
}

__device__ __forceinline__ void gload_lds16(const void* g, void* l) {
  __builtin_amdgcn_global_load_lds((const __attribute__((address_space(1))) void*)g,
                                   (__attribute__((address_space(3))) void*)l, 16, 0, 0);
}

__device__ __forceinline__ float exp2_hw(float x) {
  float r; asm("v_exp_f32 %0, %1" : "=v"(r) : "v"(x)); return r;
}

__device__ __forceinline__ unsigned cvt_pk_bf16(float lo, float hi) {
  unsigned r; asm("v_cvt_pk_bf16_f32 %0, %1, %2" : "=v"(r) : "v"(lo), "v"(hi)); return r;
}

// ---------------- fp32 -> bf16 conversion ----------------
__global__ void cvt_x(const float* __restrict__ src, short* __restrict__ dst) {
  int i = blockIdx.x * 256 + threadIdx.x;
  float4 v = ((const float4*)src)[i];
  short4 o; o.x = f2bf(v.x); o.y = f2bf(v.y); o.z = f2bf(v.z); o.w = f2bf(v.w);
  ((short4*)dst)[i] = o;
}

__global__ void cvt_w(const float* __restrict__ w0, const float* __restrict__ w1,
                      const float* __restrict__ w2, const float* __restrict__ w3,
                      short* __restrict__ d0, short* __restrict__ d1,
                      short* __restrict__ d2, short* __restrict__ d3) {
  int i = blockIdx.x * 256 + threadIdx.x;
  const float* s = blockIdx.y == 0 ? w0 : blockIdx.y == 1 ? w1 : blockIdx.y == 2 ? w2 : w3;
  short* d = blockIdx.y == 0 ? d0 : blockIdx.y == 1 ? d1 : blockIdx.y == 2 ? d2 : d3;
  float4 v = ((const float4*)s)[i];
  short4 o; o.x = f2bf(v.x); o.y = f2bf(v.y); o.z = f2bf(v.z); o.w = f2bf(v.w);
  ((short4*)d)[i] = o;
}

// ---------------- shared GEMM main loop: 128x128 tile, BK=64 ----------------
__device__ __forceinline__ void gemm_mainloop(const short* __restrict__ A,
                                              const short* __restrict__ B,
                                              int mbase, int nbase,
                                              short* As, short* Bs,
                                              f32x4 (&acc)[4][4], int lane, int w) {
  int lr = lane & 15, lg = lane >> 4;
  int wr = w >> 1, wc = w & 1;
  for (int kb = 0; kb < DIM; kb += 64) {
    if (kb) __syncthreads();
#pragma unroll
    for (int c = 0; c < 4; ++c) {
      int row = w * 32 + c * 8 + (lane >> 3);
      int sch = (lane & 7) ^ (row & 7);
      gload_lds16(A + (size_t)(mbase + row) * DIM + kb + sch * 8, (char*)As + w * 4096 + c * 1024);
      gload_lds16(B + (size_t)(nbase + row) * DIM + kb + sch * 8, (char*)Bs + w * 4096 + c * 1024);
    }
    __syncthreads();
#pragma unroll
    for (int ks = 0; ks < 2; ++ks) {
      short8 af[4], bf[4];
#pragma unroll
      for (int i = 0; i < 4; ++i) {
        int row = wr * 64 + i * 16 + lr;
        int ch = (ks * 4 + lg) ^ (row & 7);
        af[i] = *(const short8*)(As + row * 64 + ch * 8);
      }
#pragma unroll
      for (int j = 0; j < 4; ++j) {
        int row = wc * 64 + j * 16 + lr;
        int ch = (ks * 4 + lg) ^ (row & 7);
        bf[j] = *(const short8*)(Bs + row * 64 + ch * 8);
      }
#pragma unroll
      for (int i = 0; i < 4; ++i)
#pragma unroll
        for (int j = 0; j < 4; ++j)
          acc[i][j] = mfma_bf16(af[i], bf[j], acc[i][j]);
    }
  }
}

// ---------------- QKV projection ----------------
__global__ __launch_bounds__(256, 2) void gemm_qkv(const short* __restrict__ xb,
    const short* __restrict__ wq, const short* __restrict__ wk, const short* __restrict__ wv,
    short* __restrict__ Qh, short* __restrict__ Kh, short* __restrict__ Vt) {
  __shared__ __align__(16) short As[128 * 64];
  __shared__ __align__(16) short Bs[128 * 64];
  int nt = blockIdx.x, mt = blockIdx.y, z = blockIdx.z;
  const short* B = z == 0 ? wq : (z == 1 ? wk : wv);
  int tid = threadIdx.x, lane = tid & 63, w = tid >> 6;
  f32x4 acc[4][4] = {};
  gemm_mainloop(xb, B, mt * 128, nt * 128, As, Bs, acc, lane, w);
  int lr = lane & 15, lg = lane >> 4, wr = w >> 1, wc = w & 1;
  if (z < 2) {
    short* dst = z == 0 ? Qh : Kh;
#pragma unroll
    for (int i = 0; i < 4; ++i)
#pragma unroll
      for (int j = 0; j < 4; ++j) {
        int m = mt * 128 + wr * 64 + i * 16 + lg * 4;
        int n = nt * 128 + wc * 64 + j * 16 + lr;
        int bb = m >> 11, nn = m & 2047, hh = n >> 6, d = n & 63;
        size_t base = (((size_t)bb * NHEADS + hh) * NTOK + nn) * HDIM + d;
#pragma unroll
        for (int r = 0; r < 4; ++r)
          dst[base + (size_t)r * HDIM] = f2bf(acc[i][j][r]);
      }
  } else {
#pragma unroll
    for (int i = 0; i < 4; ++i)
#pragma unroll
      for (int j = 0; j < 4; ++j) {
        int m = mt * 128 + wr * 64 + i * 16 + lg * 4;
        int n = nt * 128 + wc * 64 + j * 16 + lr;
        int bb = m >> 11, nn = m & 2047, hh = n >> 6, d = n & 63;
        short4 pk;
        pk.x = f2bf(acc[i][j][0]); pk.y = f2bf(acc[i][j][1]);
        pk.z = f2bf(acc[i][j][2]); pk.w = f2bf(acc[i][j][3]);
        *(short4*)(Vt + (((size_t)bb * NHEADS + hh) * HDIM + d) * NTOK + nn) = pk;
      }
  }
}

// ---------------- fused flash attention ----------------
// 768 blocks = (qb 64) x (h 12), XCD-remapped. 4 waves/block = the 4 BATCHES
// of the same (qb,h): all waves read IDENTICAL bias addresses, barrier-aligned
// -> L1/MSHR merge serves 3 of 4 reads (bias logical traffic 805 -> 201 MB,
// the r4-r9 plateau driver). K/V per wave loaded DIRECTLY global->register
// fragments (identical layout to the old LDS path, no swizzle; L2-resident,
// ~3 MB/XCD working set). No LDS at all, no data barriers; one raw s_barrier
// per tile only to keep waves aligned for the bias merge. Math identical to
// r9 (static-max exp2-domain softmax, deferred row-sum, in-register P via
// cvt_pk + permlane32_swap).
__global__ __launch_bounds__(256, 3) void attn_fused(const short* __restrict__ Qh,
    const short* __restrict__ Kh, const short* __restrict__ Vt,
    const float* __restrict__ bias, short* __restrict__ Ob) {
  int d0 = blockIdx.x;
  int wg = (d0 & 7) * 96 + (d0 >> 3);          // bijective: 768 = 8*96
  int qb = wg & 63, h = wg >> 6;
  int tid = threadIdx.x, lane = tid & 63, w = tid >> 6;
  int ql = lane & 31, hi = lane >> 5;
  int b = w;                                    // wave = batch

  const short* Q = Qh + ((size_t)b * NHEADS + h) * NTOK * HDIM;
  const short* K = Kh + ((size_t)b * NHEADS + h) * NTOK * HDIM;
  const short* V = Vt + ((size_t)b * NHEADS + h) * HDIM * NTOK;
  int qrow = qb * 32 + ql;
  const float* Bb = bias + ((size_t)h * NTOK + qrow) * NTOK;  // b-independent!

  short8 qf[4];
#pragma unroll
  for (int i = 0; i < 4; ++i)
    qf[i] = *(const short8*)(Q + (size_t)qrow * HDIM + i * 16 + hi * 8);

  float psum = 0.f;
  f32x16 oacc0 = {}, oacc1 = {};

  for (int t = 0; t < NTOK / 64; ++t) {
    const int kv = t * 64;

    // issue K fragments for this tile (8 x 16B, L2-resident)
    short8 kf[8];
#pragma unroll
    for (int kb = 0; kb < 2; ++kb)
#pragma unroll
      for (int i = 0; i < 4; ++i)
        kf[kb * 4 + i] = *(const short8*)(K + (size_t)(kv + kb * 32 + ql) * HDIM + (i * 2 + hi) * 8);

    // issue bias (8 x dwordx4) - identical addrs across the 4 waves -> merged
    f32x4 bv[8];
#pragma unroll
    for (int g = 0; g < 8; ++g)
      bv[g] = *(const f32x4*)(Bb + kv + g * 8 + hi * 4);

    // issue V fragments for kb=0 half
    short8 vf0[4];
#pragma unroll
    for (int j = 0; j < 4; ++j)
      vf0[j] = *(const short8*)(V + (size_t)((j >> 1) * 32 + ql) * NTOK + kv + ((j & 1) * 2 + hi) * 8);

    // S^T = K Q^T : lane holds k=(reg&3)+8*(reg>>2)+4*hi (+kb*32), q=ql
    f32x16 sacc0 = {}, sacc1 = {};
    __builtin_amdgcn_s_setprio(1);
#pragma unroll
    for (int i = 0; i < 4; ++i) sacc0 = mfma32(kf[i], qf[i], sacc0);
#pragma unroll
    for (int i = 0; i < 4; ++i) sacc1 = mfma32(kf[4 + i], qf[i], sacc1);
    __builtin_amdgcn_s_setprio(0);

    // issue V fragments for kb=1 half (consumed after exp kb=1)
    short8 vf1[4];
#pragma unroll
    for (int j = 0; j < 4; ++j)
      vf1[j] = *(const short8*)(V + (size_t)((j >> 1) * 32 + ql) * NTOK + kv + (4 + (j & 1) * 2 + hi) * 8);

    // kb = 0: exp -> pack -> PV
    {
      float p[16];
#pragma unroll
      for (int rg = 0; rg < 16; ++rg) {
        float tb = fmaf(bv[rg >> 2][rg & 3], LOG2E_, -SHIFT2_);
        p[rg] = exp2_hw(fmaf(sacc0[rg], SC2_, tb));
      }
      float ts = 0.f;
#pragma unroll
      for (int g = 0; g < 4; ++g)
        ts += (p[g * 4] + p[g * 4 + 1]) + (p[g * 4 + 2] + p[g * 4 + 3]);
      psum += ts;
      unsigned Wd[4][2];
#pragma unroll
      for (int g = 0; g < 4; ++g) {
        Wd[g][0] = cvt_pk_bf16(p[g * 4], p[g * 4 + 1]);
        Wd[g][1] = cvt_pk_bf16(p[g * 4 + 2], p[g * 4 + 3]);
      }
#pragma unroll
      for (int cc = 0; cc < 2; ++cc) {
        auto r0 = __builtin_amdgcn_permlane32_swap(Wd[cc * 2][0], Wd[cc * 2 + 1][0], false, false);
        auto r1 = __builtin_amdgcn_permlane32_swap(Wd[cc * 2][1], Wd[cc * 2 + 1][1], false, false);
        union { unsigned u[4]; short8 s; } pb;
        pb.u[0] = r0[0]; pb.u[1] = r1[0]; pb.u[2] = r0[1]; pb.u[3] = r1[1];
        __builtin_amdgcn_s_setprio(1);
        oacc0 = mfma32(vf0[cc], pb.s, oacc0);
        oacc1 = mfma32(vf0[2 + cc], pb.s, oacc1);
        __builtin_amdgcn_s_setprio(0);
      }
    }
    // kb = 1
    {
      float p[16];
#pragma unroll
      for (int rg = 0; rg < 16; ++rg) {
        float tb = fmaf(bv[4 + (rg >> 2)][rg & 3], LOG2E_, -SHIFT2_);
        p[rg] = exp2_hw(fmaf(sacc1[rg], SC2_, tb));
      }
      float ts = 0.f;
#pragma unroll
      for (int g = 0; g < 4; ++g)
        ts += (p[g * 4] + p[g * 4 + 1]) + (p[g * 4 + 2] + p[g * 4 + 3]);
      psum += ts;
      unsigned Wd[4][2];
#pragma unroll
      for (int g = 0; g < 4; ++g) {
        Wd[g][0] = cvt_pk_bf16(p[g * 4], p[g * 4 + 1]);
        Wd[g][1] = cvt_pk_bf16(p[g * 4 + 2], p[g * 4 + 3]);
      }
#pragma unroll
      for (int cc = 0; cc < 2; ++cc) {
        auto r0 = __builtin_amdgcn_permlane32_swap(Wd[cc * 2][0], Wd[cc * 2 + 1][0], false, false);
        auto r1 = __builtin_amdgcn_permlane32_swap(Wd[cc * 2][1], Wd[cc * 2 + 1][1], false, false);
        union { unsigned u[4]; short8 s; } pb;
        pb.u[0] = r0[0]; pb.u[1] = r1[0]; pb.u[2] = r0[1]; pb.u[3] = r1[1];
        __builtin_amdgcn_s_setprio(1);
        oacc0 = mfma32(vf1[cc], pb.s, oacc0);
        oacc1 = mfma32(vf1[2 + cc], pb.s, oacc1);
        __builtin_amdgcn_s_setprio(0);
      }
    }

    __builtin_amdgcn_s_barrier();   // alignment only (no LDS data through it)
  }

  // epilogue: row-sum finish (one xor-32), normalize, pack, store
  float fs = psum + __shfl_xor(psum, 32);
  float inv = 1.f / fs;
  size_t obase = ((size_t)b * NTOK + qrow) * DIM + h * HDIM;
#pragma unroll
  for (int g = 0; g < 4; ++g) {
    unsigned u0 = cvt_pk_bf16(oacc0[g * 4] * inv, oacc0[g * 4 + 1] * inv);
    unsigned u1 = cvt_pk_bf16(oacc0[g * 4 + 2] * inv, oacc0[g * 4 + 3] * inv);
    uint2 pk0; pk0.x = u0; pk0.y = u1;
    *(uint2*)(Ob + obase + g * 8 + hi * 4) = pk0;
    unsigned u2 = cvt_pk_bf16(oacc1[g * 4] * inv, oacc1[g * 4 + 1] * inv);
    unsigned u3 = cvt_pk_bf16(oacc1[g * 4 + 2] * inv, oacc1[g * 4 + 3] * inv);
    uint2 pk1; pk1.x = u2; pk1.y = u3;
    *(uint2*)(Ob + obase + 32 + g * 8 + hi * 4) = pk1;
  }
}

// ---------------- output projection ----------------
__global__ __launch_bounds__(256, 2) void gemm_proj(const short* __restrict__ Ob,
    const short* __restrict__ wp, const float* __restrict__ bp, float* __restrict__ out) {
  __shared__ __align__(16) short As[128 * 64];
  __shared__ __align__(16) short Bs[128 * 64];
  int nt = blockIdx.x, mt = blockIdx.y;
  int tid = threadIdx.x, lane = tid & 63, w = tid >> 6;
  f32x4 acc[4][4] = {};
  gemm_mainloop(Ob, wp, mt * 128, nt * 128, As, Bs, acc, lane, w);
  int lr = lane & 15, lg = lane >> 4, wr = w >> 1, wc = w & 1;
#pragma unroll
  for (int j = 0; j < 4; ++j) {
    int n = nt * 128 + wc * 64 + j * 16 + lr;
    float bpv = bp[n];
#pragma unroll
    for (int i = 0; i < 4; ++i) {
      int m = mt * 128 + wr * 64 + i * 16 + lg * 4;
#pragma unroll
      for (int r = 0; r < 4; ++r)
        out[(size_t)(m + r) * DIM + n] = acc[i][j][r] + bpv;
    }
  }
}

extern "C" void kernel_launch(void* const* d_in, const int* in_sizes, int n_in,
                              void* d_out, int out_size, void* d_ws, size_t ws_size,
                              hipStream_t stream) {
  const float* x    = (const float*)d_in[0];
  const float* bias = (const float*)d_in[1];
  const float* Wq   = (const float*)d_in[2];
  const float* Wk   = (const float*)d_in[3];
  const float* Wv   = (const float*)d_in[4];
  const float* Wp   = (const float*)d_in[5];
  const float* bp   = (const float*)d_in[6];
  float* out = (float*)d_out;

  char* ws = (char*)d_ws;
  short* xb  = (short*)(ws);                    // 8192*768 bf16
  short* wqb = (short*)(ws + 12582912);
  short* wkb = (short*)(ws + 13762560);
  short* wvb = (short*)(ws + 14942208);
  short* wpb = (short*)(ws + 16121856);
  short* Qh  = (short*)(ws + 17301504);         // [b][h][n][64]
  short* Kh  = (short*)(ws + 29884416);
  short* Vt  = (short*)(ws + 42467328);         // [b][h][64][n]
  short* Ob  = (short*)(ws + 55050240);         // [b][n][768]

  cvt_x<<<6144, 256, 0, stream>>>(x, xb);
  cvt_w<<<dim3(576, 4), 256, 0, stream>>>(Wq, Wk, Wv, Wp, wqb, wkb, wvb, wpb);
  gemm_qkv<<<dim3(6, 64, 3), 256, 0, stream>>>(xb, wqb, wkb, wvb, Qh, Kh, Vt);
  attn_fused<<<768, 256, 0, stream>>>(Qh, Kh, Vt, bias, Ob);
  gemm_proj<<<dim3(6, 64), 256, 0, stream>>>(Ob, wpb, bp, out);
}

// Round 11
// 191.427 us; speedup vs baseline: 1.9476x; 1.9476x over previous
//
#include <hip/hip_runtime.h>
#include <hip/hip_bf16.h>

#define NTOK 2048
#define NHEADS 12
#define HDIM 64
#define DIM 768
#define BATCH 4
// exp2-domain: p = exp(QK*0.125 + bias - 16) = exp2(QK*SC2 + bias*LOG2E - SHIFT2)
#define SC2_    0.18033688011112042f
#define LOG2E_  1.4426950408889634f
#define SHIFT2_ 23.083120654223415f

typedef __attribute__((ext_vector_type(8))) short short8;
typedef __attribute__((ext_vector_type(4))) float f32x4;
typedef __attribute__((ext_vector_type(16))) float f32x16;

__device__ __forceinline__ short f2bf(float f) {
  union { float f; unsigned u; } v; v.f = f;
  unsigned r = v.u + 0x7fffu + ((v.u >> 16) & 1u);
  return (short)(r >> 16);
}

__device__ __forceinline__ f32x4 mfma_bf16(short8 a, short8 b, f32x4 c) {
  return __builtin_amdgcn_mfma_f32_16x16x32_bf16(a, b, c, 0, 0, 0);
}

__device__ __forceinline__ f32x16 mfma32(short8 a, short8 b, f32x16 c) {
  return __builtin_amdgcn_mfma_f32_32x32x16_bf16(a, b, c, 0, 0, 0);
}

__device__ __forceinline__ void gload_lds16(const void* g, void* l) {
  __builtin_amdgcn_global_load_lds((const __attribute__((address_space(1))) void*)g,
                                   (__attribute__((address_space(3))) void*)l, 16, 0, 0);
}

__device__ __forceinline__ float exp2_hw(float x) {
  float r; asm("v_exp_f32 %0, %1" : "=v"(r) : "v"(x)); return r;
}

__device__ __forceinline__ unsigned cvt_pk_bf16(float lo, float hi) {
  unsigned r; asm("v_cvt_pk_bf16_f32 %0, %1, %2" : "=v"(r) : "v"(lo), "v"(hi)); return r;
}

__device__ __forceinline__ int swz(int r) { return (r ^ (r >> 3)) & 7; }

// ---------------- fp32 -> bf16 conversion ----------------
__global__ void cvt_x(const float* __restrict__ src, short* __restrict__ dst) {
  int i = blockIdx.x * 256 + threadIdx.x;
  float4 v = ((const float4*)src)[i];
  short4 o; o.x = f2bf(v.x); o.y = f2bf(v.y); o.z = f2bf(v.z); o.w = f2bf(v.w);
  ((short4*)dst)[i] = o;
}

__global__ void cvt_w(const float* __restrict__ w0, const float* __restrict__ w1,
                      const float* __restrict__ w2, const float* __restrict__ w3,
                      short* __restrict__ d0, short* __restrict__ d1,
                      short* __restrict__ d2, short* __restrict__ d3) {
  int i = blockIdx.x * 256 + threadIdx.x;
  const float* s = blockIdx.y == 0 ? w0 : blockIdx.y == 1 ? w1 : blockIdx.y == 2 ? w2 : w3;
  short* d = blockIdx.y == 0 ? d0 : blockIdx.y == 1 ? d1 : blockIdx.y == 2 ? d2 : d3;
  float4 v = ((const float4*)s)[i];
  short4 o; o.x = f2bf(v.x); o.y = f2bf(v.y); o.z = f2bf(v.z); o.w = f2bf(v.w);
  ((short4*)d)[i] = o;
}

// ---------------- shared GEMM main loop: 128x128 tile, BK=64 ----------------
__device__ __forceinline__ void gemm_mainloop(const short* __restrict__ A,
                                              const short* __restrict__ B,
                                              int mbase, int nbase,
                                              short* As, short* Bs,
                                              f32x4 (&acc)[4][4], int lane, int w) {
  int lr = lane & 15, lg = lane >> 4;
  int wr = w >> 1, wc = w & 1;
  for (int kb = 0; kb < DIM; kb += 64) {
    if (kb) __syncthreads();
#pragma unroll
    for (int c = 0; c < 4; ++c) {
      int row = w * 32 + c * 8 + (lane >> 3);
      int sch = (lane & 7) ^ (row & 7);
      gload_lds16(A + (size_t)(mbase + row) * DIM + kb + sch * 8, (char*)As + w * 4096 + c * 1024);
      gload_lds16(B + (size_t)(nbase + row) * DIM + kb + sch * 8, (char*)Bs + w * 4096 + c * 1024);
    }
    __syncthreads();
#pragma unroll
    for (int ks = 0; ks < 2; ++ks) {
      short8 af[4], bf[4];
#pragma unroll
      for (int i = 0; i < 4; ++i) {
        int row = wr * 64 + i * 16 + lr;
        int ch = (ks * 4 + lg) ^ (row & 7);
        af[i] = *(const short8*)(As + row * 64 + ch * 8);
      }
#pragma unroll
      for (int j = 0; j < 4; ++j) {
        int row = wc * 64 + j * 16 + lr;
        int ch = (ks * 4 + lg) ^ (row & 7);
        bf[j] = *(const short8*)(Bs + row * 64 + ch * 8);
      }
#pragma unroll
      for (int i = 0; i < 4; ++i)
#pragma unroll
        for (int j = 0; j < 4; ++j)
          acc[i][j] = mfma_bf16(af[i], bf[j], acc[i][j]);
    }
  }
}

// ---------------- QKV projection ----------------
__global__ __launch_bounds__(256, 2) void gemm_qkv(const short* __restrict__ xb,
    const short* __restrict__ wq, const short* __restrict__ wk, const short* __restrict__ wv,
    short* __restrict__ Qh, short* __restrict__ Kh, short* __restrict__ Vt) {
  __shared__ __align__(16) short As[128 * 64];
  __shared__ __align__(16) short Bs[128 * 64];
  int nt = blockIdx.x, mt = blockIdx.y, z = blockIdx.z;
  const short* B = z == 0 ? wq : (z == 1 ? wk : wv);
  int tid = threadIdx.x, lane = tid & 63, w = tid >> 6;
  f32x4 acc[4][4] = {};
  gemm_mainloop(xb, B, mt * 128, nt * 128, As, Bs, acc, lane, w);
  int lr = lane & 15, lg = lane >> 4, wr = w >> 1, wc = w & 1;
  if (z < 2) {
    short* dst = z == 0 ? Qh : Kh;
#pragma unroll
    for (int i = 0; i < 4; ++i)
#pragma unroll
      for (int j = 0; j < 4; ++j) {
        int m = mt * 128 + wr * 64 + i * 16 + lg * 4;
        int n = nt * 128 + wc * 64 + j * 16 + lr;
        int bb = m >> 11, nn = m & 2047, hh = n >> 6, d = n & 63;
        size_t base = (((size_t)bb * NHEADS + hh) * NTOK + nn) * HDIM + d;
#pragma unroll
        for (int r = 0; r < 4; ++r)
          dst[base + (size_t)r * HDIM] = f2bf(acc[i][j][r]);
      }
  } else {
#pragma unroll
    for (int i = 0; i < 4; ++i)
#pragma unroll
      for (int j = 0; j < 4; ++j) {
        int m = mt * 128 + wr * 64 + i * 16 + lg * 4;
        int n = nt * 128 + wc * 64 + j * 16 + lr;
        int bb = m >> 11, nn = m & 2047, hh = n >> 6, d = n & 63;
        short4 pk;
        pk.x = f2bf(acc[i][j][0]); pk.y = f2bf(acc[i][j][1]);
        pk.z = f2bf(acc[i][j][2]); pk.w = f2bf(acc[i][j][3]);
        *(short4*)(Vt + (((size_t)bb * NHEADS + hh) * HDIM + d) * NTOK + nn) = pk;
      }
  }
}

// ---------------- fused flash attention ----------------
// 768 blocks (XCD-remapped). 4 waves/block, wave owns 32 q rows via 32x32x16
// MFMA (both matmuls operand-swapped, P in registers via cvt_pk+permlane).
// KVBLK=32; K, V AND BIAS all staged through LDS with contiguous
// global_load_lds (16 lines/instr, touches == unique lines) and redistributed
// to the scattered per-lane pattern via swizzled LDS reads. All three
// double-buffered in 48 KB -> 3 blocks/CU. This cuts per-CU cache-line
// touches ~40% vs direct scattered bias loads (the r4-r9 155us plateau).
__global__ __launch_bounds__(256, 3) void attn_fused(const short* __restrict__ Qh,
    const short* __restrict__ Kh, const short* __restrict__ Vt,
    const float* __restrict__ bias, short* __restrict__ Ob) {
  __shared__ __align__(16) short Ks[2][32 * 64];   // [kvrow][d]       8 KB
  __shared__ __align__(16) short Vs[2][32 * 64];   // packed V^T       8 KB
  __shared__ __align__(16) float Bs[2][128 * 32];  // [qrow][kvcol]   32 KB
  int d0 = blockIdx.x;
  int wg = (d0 & 7) * 96 + (d0 >> 3);          // bijective: 768 = 8*96
  int b = wg & 3, qb = (wg >> 2) & 15, h = wg >> 6;
  int tid = threadIdx.x, lane = tid & 63, w = tid >> 6;
  int ql = lane & 31, hi = lane >> 5;

  const short* Q = Qh + ((size_t)b * NHEADS + h) * NTOK * HDIM;
  const short* K = Kh + ((size_t)b * NHEADS + h) * NTOK * HDIM;
  const short* V = Vt + ((size_t)b * NHEADS + h) * HDIM * NTOK;
  int qrow = qb * 128 + w * 32 + ql;
  const float* Bg = bias + ((size_t)h * NTOK + qb * 128) * NTOK;  // block rows

  short8 qf[4];
#pragma unroll
  for (int i = 0; i < 4; ++i)
    qf[i] = *(const short8*)(Q + (size_t)qrow * HDIM + i * 16 + hi * 8);

  float psum = 0.f;
  f32x16 oacc0 = {}, oacc1 = {};

  int l8 = lane >> 3, s7 = lane & 7;

#define STAGE_ALL(BUF, KV)                                                     \
  {                                                                            \
    /* K: 32 rows x 128B, 1 instr/wave, linear [row][chunk] + src swizzle */   \
    int krow = w * 8 + l8;                                                     \
    gload_lds16(K + (size_t)(KV + krow) * HDIM + ((s7 ^ swz(krow)) * 8),       \
                (char*)Ks[BUF] + w * 1024);                                    \
    /* V: packed [row'=d>>1][(d&1)*4+cg chunks], 1 instr/wave */               \
    int vrp = w * 8 + l8;                                                      \
    int vu = s7 ^ swz(vrp);                                                    \
    gload_lds16(V + (size_t)(vrp * 2 + (vu >> 2)) * NTOK + (KV) + (vu & 3) * 8,\
                (char*)Vs[BUF] + w * 1024);                                    \
    /* bias: 128 rows x 128B, 4 instr/wave */                                  \
    _Pragma("unroll")                                                          \
    for (int j = 0; j < 4; ++j) {                                              \
      int brow = w * 32 + j * 8 + l8;                                          \
      gload_lds16(Bg + (size_t)brow * NTOK + (KV) + ((s7 ^ swz(brow)) * 4),    \
                  (char*)Bs[BUF] + w * 4096 + j * 1024);                       \
    }                                                                          \
  }

  STAGE_ALL(0, 0)
  __syncthreads();

  for (int t = 0; t < NTOK / 32; ++t) {
    int cur = t & 1;
    int kv = t * 32;
    if (t < NTOK / 32 - 1) STAGE_ALL(cur ^ 1, kv + 32)

    // S^T = K Q^T : lane holds k = (reg&3)+8*(reg>>2)+4*hi, q = ql
    f32x16 sacc = {};
    __builtin_amdgcn_s_setprio(1);
#pragma unroll
    for (int i = 0; i < 4; ++i) {
      short8 kf = *(const short8*)(Ks[cur] + ql * 64 + (((i * 2 + hi) ^ swz(ql)) * 8));
      sacc = mfma32(kf, qf[i], sacc);
    }
    __builtin_amdgcn_s_setprio(0);

    // bias from LDS: bvr[g] = bias[qrow][8g + 4hi + 0..3]
    f32x4 bvr[4];
    int brow = w * 32 + ql;
#pragma unroll
    for (int g = 0; g < 4; ++g)
      bvr[g] = *(const f32x4*)(Bs[cur] + brow * 32 + (((g * 2 + hi) ^ swz(brow)) * 4));

    // p = exp2(S*SC2 + bias*LOG2E - SHIFT2)
    float p[16];
#pragma unroll
    for (int rg = 0; rg < 16; ++rg) {
      float tb = fmaf(bvr[rg >> 2][rg & 3], LOG2E_, -SHIFT2_);
      p[rg] = exp2_hw(fmaf(sacc[rg], SC2_, tb));
    }
    float ts = 0.f;
#pragma unroll
    for (int g = 0; g < 4; ++g)
      ts += (p[g * 4] + p[g * 4 + 1]) + (p[g * 4 + 2] + p[g * 4 + 3]);
    psum += ts;

    unsigned Wd[4][2];
#pragma unroll
    for (int g = 0; g < 4; ++g) {
      Wd[g][0] = cvt_pk_bf16(p[g * 4], p[g * 4 + 1]);
      Wd[g][1] = cvt_pk_bf16(p[g * 4 + 2], p[g * 4 + 3]);
    }

    // PV: rebuild B-frag via permlane32_swap; A = packed V^T rows from LDS
#pragma unroll
    for (int cc = 0; cc < 2; ++cc) {
      auto r0 = __builtin_amdgcn_permlane32_swap(Wd[cc * 2][0], Wd[cc * 2 + 1][0], false, false);
      auto r1 = __builtin_amdgcn_permlane32_swap(Wd[cc * 2][1], Wd[cc * 2 + 1][1], false, false);
      union { unsigned u[4]; short8 s; } pb;
      pb.u[0] = r0[0]; pb.u[1] = r1[0]; pb.u[2] = r0[1]; pb.u[3] = r1[1];
      __builtin_amdgcn_s_setprio(1);
      {
        int rp0 = (ql >> 1);
        int s0 = (((ql & 1) * 4 + cc * 2 + hi) ^ swz(rp0));
        short8 vf0 = *(const short8*)(Vs[cur] + rp0 * 64 + s0 * 8);
        oacc0 = mfma32(vf0, pb.s, oacc0);
        int rp1 = 16 + (ql >> 1);
        int s1 = (((ql & 1) * 4 + cc * 2 + hi) ^ swz(rp1));
        short8 vf1 = *(const short8*)(Vs[cur] + rp1 * 64 + s1 * 8);
        oacc1 = mfma32(vf1, pb.s, oacc1);
      }
      __builtin_amdgcn_s_setprio(0);
    }

    __syncthreads();
  }
#undef STAGE_ALL

  // epilogue: row-sum finish (one xor-32), normalize, pack, store
  float fs = psum + __shfl_xor(psum, 32);
  float inv = 1.f / fs;
  size_t obase = ((size_t)b * NTOK + qrow) * DIM + h * HDIM;
#pragma unroll
  for (int g = 0; g < 4; ++g) {
    unsigned u0 = cvt_pk_bf16(oacc0[g * 4] * inv, oacc0[g * 4 + 1] * inv);
    unsigned u1 = cvt_pk_bf16(oacc0[g * 4 + 2] * inv, oacc0[g * 4 + 3] * inv);
    uint2 pk0; pk0.x = u0; pk0.y = u1;
    *(uint2*)(Ob + obase + g * 8 + hi * 4) = pk0;
    unsigned u2 = cvt_pk_bf16(oacc1[g * 4] * inv, oacc1[g * 4 + 1] * inv);
    unsigned u3 = cvt_pk_bf16(oacc1[g * 4 + 2] * inv, oacc1[g * 4 + 3] * inv);
    uint2 pk1; pk1.x = u2; pk1.y = u3;
    *(uint2*)(Ob + obase + 32 + g * 8 + hi * 4) = pk1;
  }
}

// ---------------- output projection ----------------
__global__ __launch_bounds__(256, 2) void gemm_proj(const short* __restrict__ Ob,
    const short* __restrict__ wp, const float* __restrict__ bp, float* __restrict__ out) {
  __shared__ __align__(16) short As[128 * 64];
  __shared__ __align__(16) short Bs[128 * 64];
  int nt = blockIdx.x, mt = blockIdx.y;
  int tid = threadIdx.x, lane = tid & 63, w = tid >> 6;
  f32x4 acc[4][4] = {};
  gemm_mainloop(Ob, wp, mt * 128, nt * 128, As, Bs, acc, lane, w);
  int lr = lane & 15, lg = lane >> 4, wr = w >> 1, wc = w & 1;
#pragma unroll
  for (int j = 0; j < 4; ++j) {
    int n = nt * 128 + wc * 64 + j * 16 + lr;
    float bpv = bp[n];
#pragma unroll
    for (int i = 0; i < 4; ++i) {
      int m = mt * 128 + wr * 64 + i * 16 + lg * 4;
#pragma unroll
      for (int r = 0; r < 4; ++r)
        out[(size_t)(m + r) * DIM + n] = acc[i][j][r] + bpv;
    }
  }
}

extern "C" void kernel_launch(void* const* d_in, const int* in_sizes, int n_in,
                              void* d_out, int out_size, void* d_ws, size_t ws_size,
                              hipStream_t stream) {
  const float* x    = (const float*)d_in[0];
  const float* bias = (const float*)d_in[1];
  const float* Wq   = (const float*)d_in[2];
  const float* Wk   = (const float*)d_in[3];
  const float* Wv   = (const float*)d_in[4];
  const float* Wp   = (const float*)d_in[5];
  const float* bp   = (const float*)d_in[6];
  float* out = (float*)d_out;

  char* ws = (char*)d_ws;
  short* xb  = (short*)(ws);                    // 8192*768 bf16
  short* wqb = (short*)(ws + 12582912);
  short* wkb = (short*)(ws + 13762560);
  short* wvb = (short*)(ws + 14942208);
  short* wpb = (short*)(ws + 16121856);
  short* Qh  = (short*)(ws + 17301504);         // [b][h][n][64]
  short* Kh  = (short*)(ws + 29884416);
  short* Vt  = (short*)(ws + 42467328);         // [b][h][64][n]
  short* Ob  = (short*)(ws + 55050240);         // [b][n][768]

  cvt_x<<<6144, 256, 0, stream>>>(x, xb);
  cvt_w<<<dim3(576, 4), 256, 0, stream>>>(Wq, Wk, Wv, Wp, wqb, wkb, wvb, wpb);
  gemm_qkv<<<dim3(6, 64, 3), 256, 0, stream>>>(xb, wqb, wkb, wvb, Qh, Kh, Vt);
  attn_fused<<<768, 256, 0, stream>>>(Qh, Kh, Vt, bias, Ob);
  gemm_proj<<<dim3(6, 64), 256, 0, stream>>>(Ob, wpb, bp, out);
}